// Round 12
// baseline (262.400 us; speedup 1.0000x reference)
//
#include <hip/hip_runtime.h>
#include <hip/hip_bf16.h>

// Problem constants
#define B_    8
#define NT_   8192
#define NS_   2048
#define NTOT  (B_ * NT_)    // 65536 target points
#define CTGT  128
#define CSRC  256
#define CIN   384           // CTGT + CSRC
#define CHID  256
#define COUT  128

typedef __bf16 bf16x8 __attribute__((ext_vector_type(8)));
typedef float  f32x4  __attribute__((ext_vector_type(4)));

__device__ inline unsigned short f2bf(float f) {
    unsigned int u = __float_as_uint(f);
    u += 0x7FFF + ((u >> 16) & 1);   // round-to-nearest-even
    return (unsigned short)(u >> 16);
}

// async global->LDS, 16B per lane, dest = wave-uniform base + lane*16
__device__ __forceinline__ void gload16(const unsigned short* g, unsigned short* l) {
    __builtin_amdgcn_global_load_lds(
        (const __attribute__((address_space(1))) unsigned int*)g,
        (__attribute__((address_space(3))) unsigned int*)l, 16, 0, 0);
}

// ---------------------------------------------------------------------------
// K0: build bf16 transposed weight matrices in workspace.
// ---------------------------------------------------------------------------
__global__ __launch_bounds__(256) void prep_weights(
    const float* __restrict__ W1, const float* __restrict__ Ws,
    const float* __restrict__ W2,
    unsigned short* __restrict__ Wct, unsigned short* __restrict__ W2t) {
    int g = blockIdx.x * 256 + threadIdx.x;
    if (g < CIN * CIN) {
        int n = g / CIN, k = g % CIN;
        float v = (n < CHID) ? W1[(size_t)k * CHID + n]
                             : Ws[(size_t)k * COUT + (n - CHID)];
        Wct[g] = f2bf(v);
    } else {
        int g2 = g - CIN * CIN;
        if (g2 < COUT * CHID) {
            int n = g2 / CHID, k = g2 % CHID;
            W2t[g2] = f2bf(W2[(size_t)k * COUT + n]);
        }
    }
}

// ---------------------------------------------------------------------------
// K1: brute-force KNN, 4 targets per thread (amortize ds_read + loop overhead
// over 4 pairs). Selection per chain identical to round-9-validated branchless
// insert (strict <, ascending j, chunk-ascending merge -> same tie-break).
// Block = 32 target-lanes x 8 chunks; covers 128 targets; grid 512.
// Merge scratch (24 KB) overlays ps4 after a barrier.
// ---------------------------------------------------------------------------
__global__ __launch_bounds__(256) void knn_kernel(
    const float* __restrict__ pos_t, const float* __restrict__ pos_s,
    int* __restrict__ knn_i, float* __restrict__ knn_d) {
    __shared__ char smem[32768];
    float4* ps4 = (float4*)smem;                 // phase 1: 2048 x 16B = 32 KB
    float*  md  = (float*)smem;                  // phase 2: 128*8*3 f32 = 12 KB
    int*    mi  = (int*)(smem + 12288);          // phase 2: 12 KB

    int blk = blockIdx.x;                        // 512 blocks
    int batch = blk >> 6;                        // 64 blocks per batch
    const float* src = pos_s + (size_t)batch * NS_ * 3;
    for (int i = threadIdx.x; i < NS_; i += 256) {
        ps4[i] = make_float4(src[i * 3 + 0], src[i * 3 + 1], src[i * 3 + 2], 0.0f);
    }
    __syncthreads();

    int tl = threadIdx.x & 31;
    int ck = threadIdx.x >> 5;                   // chunk 0..7
    int t0 = blk * 128 + tl;
    float px[4], py[4], pz[4];
#pragma unroll
    for (int q = 0; q < 4; ++q) {
        px[q] = pos_t[(t0 + q * 32) * 3 + 0];
        py[q] = pos_t[(t0 + q * 32) * 3 + 1];
        pz[q] = pos_t[(t0 + q * 32) * 3 + 2];
    }
    float e0[4], e1[4], e2[4];
    int j0[4], j1[4], j2[4];
#pragma unroll
    for (int q = 0; q < 4; ++q) {
        e0[q] = e1[q] = e2[q] = 3.4e38f;
        j0[q] = j1[q] = j2[q] = 0;
    }

    int jbeg = ck * 256, jend = jbeg + 256;
#pragma unroll 2
    for (int j = jbeg; j < jend; ++j) {
        float4 p = ps4[j];
#pragma unroll
        for (int q = 0; q < 4; ++q) {
            float dx = __fsub_rn(px[q], p.x);
            float dy = __fsub_rn(py[q], p.y);
            float dz = __fsub_rn(pz[q], p.z);
            float d = __fadd_rn(__fadd_rn(__fmul_rn(dx, dx), __fmul_rn(dy, dy)),
                                __fmul_rn(dz, dz));
            bool c0 = d < e0[q], c1 = d < e1[q], c2 = d < e2[q];
            int n2i = c2 ? (c1 ? j1[q] : j) : j2[q];
            int n1i = c1 ? (c0 ? j0[q] : j) : j1[q];
            int n0i = c0 ? j : j0[q];
            float v2 = __builtin_amdgcn_fmed3f(d, e1[q], e2[q]);
            float v1 = __builtin_amdgcn_fmed3f(d, e0[q], e1[q]);
            float v0 = fminf(e0[q], d);
            e0[q] = v0; e1[q] = v1; e2[q] = v2;
            j0[q] = n0i; j1[q] = n1i; j2[q] = n2i;
        }
    }
    __syncthreads();   // all ps4 reads done before overwriting with md/mi

#pragma unroll
    for (int q = 0; q < 4; ++q) {
        int slot = ((tl + q * 32) * 8 + ck) * 3;
        md[slot + 0] = e0[q]; md[slot + 1] = e1[q]; md[slot + 2] = e2[q];
        mi[slot + 0] = j0[q]; mi[slot + 1] = j1[q]; mi[slot + 2] = j2[q];
    }
    __syncthreads();

    if (threadIdx.x < 128) {
        int tloc = threadIdx.x;
        int t = blk * 128 + tloc;
        int base = tloc * 24;
        float E0 = md[base + 0], E1 = md[base + 1], E2 = md[base + 2];
        int   J0 = mi[base + 0], J1 = mi[base + 1], J2 = mi[base + 2];
#pragma unroll
        for (int c = 1; c < 8; ++c) {
#pragma unroll
            for (int rr = 0; rr < 3; ++rr) {
                float d = md[base + c * 3 + rr];
                int   i = mi[base + c * 3 + rr];
                bool c0 = d < E0, c1 = d < E1, c2 = d < E2;
                int n2i = c2 ? (c1 ? J1 : i) : J2;
                int n1i = c1 ? (c0 ? J0 : i) : J1;
                int n0i = c0 ? i : J0;
                float ne2 = __builtin_amdgcn_fmed3f(d, E1, E2);
                float ne1 = __builtin_amdgcn_fmed3f(d, E0, E1);
                float ne0 = fminf(E0, d);
                E0 = ne0; E1 = ne1; E2 = ne2;
                J0 = n0i; J1 = n1i; J2 = n2i;
            }
        }
        knn_i[t * 3 + 0] = J0; knn_i[t * 3 + 1] = J1; knn_i[t * 3 + 2] = J2;
        knn_d[t * 3 + 0] = E0; knn_d[t * 3 + 1] = E1; knn_d[t * 3 + 2] = E2;
    }
}

// ---------------------------------------------------------------------------
// K2: interpolate + concat -> combined bf16 [NTOT][384]  (unchanged).
// ---------------------------------------------------------------------------
__global__ __launch_bounds__(256) void interp_kernel(
    const float* __restrict__ x_t, const float* __restrict__ x_s,
    const int* __restrict__ knn_i, const float* __restrict__ knn_d,
    unsigned short* __restrict__ combined) {
    int g = blockIdx.x * 256 + threadIdx.x;
    int row = g / 96, seg = g % 96;
    if (row >= NTOT) return;
    if (seg < 32) {
        float4 v = *(const float4*)(x_t + (size_t)row * CTGT + seg * 4);
        ushort4 o;
        o.x = f2bf(v.x); o.y = f2bf(v.y); o.z = f2bf(v.z); o.w = f2bf(v.w);
        *(ushort4*)(combined + (size_t)row * CIN + seg * 4) = o;
    } else {
        int c = (seg - 32) * 4;
        int batch = row >> 13;
        const float* xsb = x_s + (size_t)batch * NS_ * CSRC;
        int i0 = knn_i[row * 3 + 0];
        int i1 = knn_i[row * 3 + 1];
        int i2 = knn_i[row * 3 + 2];
        float w0 = 1.0f / fmaxf(knn_d[row * 3 + 0], 1e-16f);
        float w1 = 1.0f / fmaxf(knn_d[row * 3 + 1], 1e-16f);
        float w2 = 1.0f / fmaxf(knn_d[row * 3 + 2], 1e-16f);
        float inv = 1.0f / (w0 + w1 + w2);
        float4 a = *(const float4*)(xsb + (size_t)i0 * CSRC + c);
        float4 b = *(const float4*)(xsb + (size_t)i1 * CSRC + c);
        float4 d = *(const float4*)(xsb + (size_t)i2 * CSRC + c);
        ushort4 o;
        o.x = f2bf((w0 * a.x + w1 * b.x + w2 * d.x) * inv);
        o.y = f2bf((w0 * a.y + w1 * b.y + w2 * d.y) * inv);
        o.z = f2bf((w0 * a.z + w1 * b.z + w2 * d.z) * inv);
        o.w = f2bf((w0 * a.w + w1 * b.w + w2 * d.w) * inv);
        *(ushort4*)(combined + (size_t)row * CIN + CTGT + c) = o;
    }
}

// ---------------------------------------------------------------------------
// K3: FUSED MLP: per 128-row M-tile, gemm1 (N=384, K=384) with h->LDS and
// res->registers, then gemm2 (N=128, K=256) accumulating INTO res, epilogue
// relu(acc + b2 + bs) -> out. Eliminates hbuf/resbuf HBM round-trip (136 MB).
//
// 512 threads = 8 waves, grid 2(M)x4(N). Stage-1 wave cols n = wn*16 + j*64
// (j=0..5); j>=4 are the res cols, which ARE the wave's stage-2 output cols
// (n2 = wn*16 + f*64) -> res never leaves registers (MFMA C-in chaining).
//
// Dynamic LDS 80 KB:
//   [0,16K)  stage-1 A dbuf [2][128x32]   } after ep-1: h bf16 [128][256]
//   [16K,64K) stage-1 B dbuf [2][384x32]  }   (XOR-swizzled, both sides)
//   [64K,80K) stage-2 B2 dbuf [2][128x32]
// h swizzle: phys_col = (c & ~63) | ((c&63) ^ ((row&7)<<3)) -> ds_read_b128
// across 16 rows hits 8 distinct 16B slots (2-way = free).
// ---------------------------------------------------------------------------
__device__ __forceinline__ void stage1_ld(
    const unsigned short* __restrict__ ga, const unsigned short* __restrict__ Wct,
    unsigned short* Asm, unsigned short* Bsm,
    int k0, int buf, int widu, int rloc, int cswz) {
    gload16(ga + (size_t)(widu * 16 + rloc) * CIN + k0 + cswz,
            Asm + buf * 4096 + widu * 512);
#pragma unroll
    for (int p = 0; p < 3; ++p)
        gload16(Wct + (size_t)(p * 128 + widu * 16 + rloc) * CIN + k0 + cswz,
                Bsm + buf * 12288 + (p * 8 + widu) * 512);
}

__global__ __launch_bounds__(512) void mlp_fused(
    const unsigned short* __restrict__ A, const unsigned short* __restrict__ Wct,
    const unsigned short* __restrict__ W2t,
    const float* __restrict__ b1, const float* __restrict__ bs,
    const float* __restrict__ b2, float* __restrict__ out) {
    extern __shared__ char smem[];
    unsigned short* Asm  = (unsigned short*)smem;             // stage-1 A dbuf
    unsigned short* Bsm  = (unsigned short*)(smem + 16384);   // stage-1 B dbuf
    unsigned short* Hsm  = (unsigned short*)smem;             // h (overlays A/B)
    unsigned short* B2sm = (unsigned short*)(smem + 65536);   // stage-2 B dbuf

    int tid = threadIdx.x;
    int wid = tid >> 6, lane = tid & 63;
    int widu = __builtin_amdgcn_readfirstlane(wid);
    int wm = widu >> 2, wn = widu & 3;
    int r = lane & 15, g = lane >> 4;
    int kcol = (g * 8) ^ (((r >> 1) & 3) * 8);
    int rloc = lane >> 2;
    int cswz = ((lane & 3) ^ ((lane >> 3) & 3)) * 8;

    const unsigned short* ga = A + (size_t)(blockIdx.x * 128) * CIN;

    f32x4 acc[4][6] = {};

    // ---------------- stage 1: [128x384] = A[128x384k] @ Wc ----------------
    stage1_ld(ga, Wct, Asm, Bsm, 0, 0, widu, rloc, cswz);
    __syncthreads();
    int cur = 0;
#pragma unroll 1
    for (int t = 0; t < 12; ++t) {
        if (t + 1 < 12) {
            stage1_ld(ga, Wct, Asm, Bsm, (t + 1) * 32, cur ^ 1, widu, rloc, cswz);
        } else {
            // prefetch stage-2 B2 k-step 0 (region untouched by stage 1)
            gload16(W2t + (size_t)(widu * 16 + rloc) * CHID + cswz,
                    B2sm + widu * 512);
        }
        bf16x8 af[4], bf[6];
#pragma unroll
        for (int mi = 0; mi < 4; ++mi)
            af[mi] = *(const bf16x8*)(Asm + cur * 4096 + (wm * 64 + mi * 16 + r) * 32 + kcol);
#pragma unroll
        for (int j = 0; j < 6; ++j)
            bf[j] = *(const bf16x8*)(Bsm + cur * 12288 + (wn * 16 + j * 64 + r) * 32 + kcol);
#pragma unroll
        for (int mi = 0; mi < 4; ++mi)
#pragma unroll
            for (int j = 0; j < 6; ++j)
                acc[mi][j] = __builtin_amdgcn_mfma_f32_16x16x32_bf16(
                    af[mi], bf[j], acc[mi][j], 0, 0, 0);
        __syncthreads();
        cur ^= 1;
    }

    // ---------------- epilogue 1: h -> LDS (relu+b1, bf16); res stays in acc[.][4,5]
#pragma unroll
    for (int mi = 0; mi < 4; ++mi)
#pragma unroll
        for (int j = 0; j < 4; ++j) {
            int n = wn * 16 + j * 64 + r;       // 0..255
            float bb = b1[n];
#pragma unroll
            for (int rr = 0; rr < 4; ++rr) {
                int m = wm * 64 + mi * 16 + g * 4 + rr;
                float v = fmaxf(acc[mi][j][rr] + bb, 0.0f);
                int np = (n & ~63) | ((n & 63) ^ ((m & 7) << 3));
                Hsm[m * 256 + np] = f2bf(v);
            }
        }
    __syncthreads();

    // ---------------- stage 2: out[128x128] = relu(h @ W2 + res + b2 + bs)
    int cur2 = 0;
#pragma unroll 1
    for (int t = 0; t < 8; ++t) {
        if (t + 1 < 8)
            gload16(W2t + (size_t)(widu * 16 + rloc) * CHID + (t + 1) * 32 + cswz,
                    B2sm + (cur2 ^ 1) * 4096 + widu * 512);
        bf16x8 af2[4], bf2[2];
#pragma unroll
        for (int mi = 0; mi < 4; ++mi) {
            int m = wm * 64 + mi * 16 + r;
            int c = t * 32 + g * 8;
            int np = (c & ~63) | ((c & 63) ^ ((m & 7) << 3));
            af2[mi] = *(const bf16x8*)(Hsm + m * 256 + np);
        }
#pragma unroll
        for (int f = 0; f < 2; ++f)
            bf2[f] = *(const bf16x8*)(B2sm + cur2 * 4096 + (wn * 16 + f * 64 + r) * 32 + kcol);
#pragma unroll
        for (int mi = 0; mi < 4; ++mi)
#pragma unroll
            for (int f = 0; f < 2; ++f)
                acc[mi][4 + f] = __builtin_amdgcn_mfma_f32_16x16x32_bf16(
                    af2[mi], bf2[f], acc[mi][4 + f], 0, 0, 0);
        __syncthreads();
        cur2 ^= 1;
    }

    // ---------------- epilogue 2
#pragma unroll
    for (int mi = 0; mi < 4; ++mi)
#pragma unroll
        for (int f = 0; f < 2; ++f) {
            int n = wn * 16 + f * 64 + r;       // 0..127
            float bb = b2[n] + bs[n];
#pragma unroll
            for (int rr = 0; rr < 4; ++rr) {
                int m = wm * 64 + mi * 16 + g * 4 + rr;
                float v = acc[mi][4 + f][rr] + bb;
                out[(size_t)(blockIdx.x * 128 + m) * COUT + n] = fmaxf(v, 0.0f);
            }
        }
}

// ---------------------------------------------------------------------------
extern "C" void kernel_launch(void* const* d_in, const int* in_sizes, int n_in,
                              void* d_out, int out_size, void* d_ws, size_t ws_size,
                              hipStream_t stream) {
    const float* x_t   = (const float*)d_in[0];
    const float* pos_t = (const float*)d_in[1];
    const float* x_s   = (const float*)d_in[3];
    const float* pos_s = (const float*)d_in[4];
    const float* W1    = (const float*)d_in[6];
    const float* b1    = (const float*)d_in[7];
    const float* W2    = (const float*)d_in[8];
    const float* b2    = (const float*)d_in[9];
    const float* Ws    = (const float*)d_in[10];
    const float* bs    = (const float*)d_in[11];

    char* ws = (char*)d_ws;
    int*            knn_i = (int*)           (ws + 0);           //  786,432
    float*          knn_d = (float*)         (ws + 786432);      //  786,432
    unsigned short* Wct   = (unsigned short*)(ws + 1572864);     //  294,912
    unsigned short* W2t   = (unsigned short*)(ws + 1867776);     //   65,536
    unsigned short* comb  = (unsigned short*)(ws + 1933312);     // 50,331,648
    float*          out   = (float*)d_out;

    // allow 80 KB dynamic LDS for the fused kernel (host-side, capture-safe)
    hipFuncSetAttribute((const void*)mlp_fused,
                        hipFuncAttributeMaxDynamicSharedMemorySize, 81920);

    prep_weights<<<704, 256, 0, stream>>>(W1, Ws, W2, Wct, W2t);
    knn_kernel<<<NTOT / 128, 256, 0, stream>>>(pos_t, pos_s, knn_i, knn_d);
    interp_kernel<<<(NTOT * 96) / 256, 256, 0, stream>>>(x_t, x_s, knn_i, knn_d, comb);
    mlp_fused<<<512, 512, 81920, stream>>>(comb, Wct, W2t, b1, bs, b2, out);
}